// Round 22
// baseline (159.624 us; speedup 1.0000x reference)
//
#include <hip/hip_runtime.h>
#include <hip/hip_bf16.h>

#define NTOK 4096
#define SCALE 0.17677669529663687f  /* 32^-0.5 */

// 16B-chunk XOR swizzle within a 64B (32-ushort) LDS row (K6 tiles).
#define SWZ(r) ((((r) >> 1) ^ ((r) >> 3)) & 3)

using f32x4 = __attribute__((ext_vector_type(4))) float;
using s16x8 = __attribute__((ext_vector_type(8))) short;
using v4i   = __attribute__((ext_vector_type(4))) int;

__device__ __forceinline__ ushort bf_rne(float f) {
  unsigned int u = __builtin_bit_cast(unsigned int, f);
  u += 0x7FFFu + ((u >> 16) & 1u);
  return (ushort)(u >> 16);
}
__device__ __forceinline__ unsigned int pk2(float a, float b) {
  __hip_bfloat162 h = __float22bfloat162_rn(make_float2(a, b));
  unsigned int u;
  __builtin_memcpy(&u, &h, 4);
  return u;
}
__device__ __forceinline__ void gl_lds16(const ushort* g, ushort* l) {
  __builtin_amdgcn_global_load_lds(
      (const __attribute__((address_space(1))) unsigned int*)g,
      (__attribute__((address_space(3))) unsigned int*)l, 16, 0, 0);
}
__device__ __forceinline__ v4i make_srsrc(const void* p) {
  union {
    struct { const void* p; unsigned nr; unsigned fl; } s;
    v4i v;
  } u;
  u.s.p = p;
  u.s.nr = 0xFFFFFFFFu;
  u.s.fl = 0x00020000u;
  return u.v;
}
#if __has_builtin(__builtin_amdgcn_raw_buffer_load_f32)
#define HAVE_RAW_BL 1
#else
#define HAVE_RAW_BL 0
#endif

// ---------------------------------------------------------------------------
// K0: w_qkv (384x256 f32) -> bf16 RNE. grid 96 x 256.
// ---------------------------------------------------------------------------
__global__ __launch_bounds__(256) void k_cvt_w(const float* __restrict__ w,
                                               ushort* __restrict__ wb) {
  const int i = blockIdx.x * 256 + threadIdx.x;
  const float4 v = reinterpret_cast<const float4*>(w)[i];
  ushort4 h;
  h.x = bf_rne(v.x); h.y = bf_rne(v.y); h.z = bf_rne(v.z); h.w = bf_rne(v.w);
  reinterpret_cast<ushort4*>(wb)[i] = h;
}

// ---------------------------------------------------------------------------
// K1 (A-persistent, BK=64, 8 waves, XCD-coherent panel swizzle):
// qkv = w @ x from x f32 [c][n]. Flat grid (96, 32): F = g*24 + y*8 + r,
// n_tile = g*8 + r, o = y -- the 3 o-blocks sharing an x-panel have ids
// differing by 8 => SAME XCD (F%8 = r) and temporally adjacent => the
// 2nd/3rd panel reads hit hot L2 instead of going to L3 (cuts aggregate
// L2-miss traffic up to 3x). Kernel body identical to round 21.
// ---------------------------------------------------------------------------
__global__ __launch_bounds__(512) void k_qkv_mfma(const float* __restrict__ x,
                                                  const ushort* __restrict__ wb,
                                                  ushort* __restrict__ Ecn,
                                                  ushort* __restrict__ kb,
                                                  ushort* __restrict__ vb,
                                                  float* __restrict__ spart) {
  const int F = blockIdx.x;          // 0..95
  const int g = F / 24;
  const int rem = F % 24;
  const int y = rem >> 3;            // o-tile 0..2
  const int r = rem & 7;
  const int ntile = g * 8 + r;       // 0..31
  const int n0 = ntile * 128;
  const int o0 = y * 128;
  const int b  = blockIdx.y;
  const float* xb = x + (size_t)b * 256 * NTOK;

  __shared__ ushort As[128 * 256];  // 64KB: [o-row][c], 32 chunks/row, ^(row&31)
  __shared__ ushort Bs[128 * 64];   // 16KB: [n][64c], 8 chunks/row, ^(n&7)

  const int t = threadIdx.x;
  const int lane = t & 63;
  const int wv = t >> 6;            // 0..7
  const int wr = wv & 3;            // row group (32 rows)
  const int wc = wv >> 2;           // col half (64 cols)
  const int lm = lane & 15;
  const int lk = lane >> 4;

  int arow[2], brow[4];
#pragma unroll
  for (int mf = 0; mf < 2; ++mf) arow[mf] = wr * 32 + mf * 16 + lm;
#pragma unroll
  for (int nf = 0; nf < 4; ++nf) brow[nf] = wc * 64 + nf * 16 + lm;

  // B staging: unit u = t + 512*i (i<2) -> (n = u&127, c-oct = u>>7, 0..7)
  int sst[2], sn[2], sco[2];
#pragma unroll
  for (int i = 0; i < 2; ++i) {
    const int u = t + 512 * i;
    sn[i] = u & 127;
    sco[i] = u >> 7;
    sst[i] = sn[i] * 64 + 8 * (sco[i] ^ (sn[i] & 7));
  }
  const float* xbn = xb + n0;
  const v4i rx = make_srsrc(xbn);
  int voff[2];
#pragma unroll
  for (int i = 0; i < 2; ++i) voff[i] = (sco[i] * 8 * NTOK + sn[i]) * 4;

#if HAVE_RAW_BL
#define BLOAD(i, j, itc) __builtin_amdgcn_raw_buffer_load_f32(rx, voff[i], (itc) * 1048576 + (j) * 16384, 0)
#else
#define BLOAD(i, j, itc) xbn[(size_t)((itc) * 64 + sco[i] * 8 + (j)) * NTOK + sn[i]]
#endif

  // ---- prologue: stage ALL of A once; P(0); drain; then issue P(1) ----
#pragma unroll
  for (int i = 0; i < 8; ++i) {
    const int s = i * 512 + t;
    const int row = s >> 5;
    const int q = (s & 31) ^ (row & 31);
    gl_lds16(wb + (size_t)(o0 + row) * 256 + q * 8,
             As + (size_t)(i * 512 + wv * 64) * 8);
  }
  float preA[16], preB[16];
#pragma unroll
  for (int i = 0; i < 2; ++i)
#pragma unroll
    for (int j = 0; j < 8; ++j) preA[i * 8 + j] = BLOAD(i, j, 0);
  __syncthreads();  // drains A gl_lds + P(0); one-time cost
#pragma unroll
  for (int i = 0; i < 2; ++i)
#pragma unroll
    for (int j = 0; j < 8; ++j) preB[i * 8 + j] = BLOAD(i, j, 1);

  f32x4 acc[2][4];
#pragma unroll
  for (int i = 0; i < 2; ++i)
#pragma unroll
    for (int j = 0; j < 4; ++j) acc[i][j] = (f32x4){0.f, 0.f, 0.f, 0.f};

#pragma unroll
  for (int it = 0; it < 4; ++it) {
    // ---- land P(it): counted wait keeps P(it+1) in flight ----
    if (it >= 1) {
      __builtin_amdgcn_sched_barrier(0);
      if (it < 3) {
        asm volatile("s_waitcnt vmcnt(16)" ::: "memory");
      } else {
        asm volatile("s_waitcnt vmcnt(0)" ::: "memory");
      }
      __builtin_amdgcn_sched_barrier(0);
    }
    // ---- stage B from P(it) regs ----
    float* cur = (it & 1) ? preB : preA;
#pragma unroll
    for (int i = 0; i < 2; ++i) {
      union { s16x8 v; unsigned int u[4]; } pk;
      pk.u[0] = pk2(cur[i * 8 + 0], cur[i * 8 + 1]);
      pk.u[1] = pk2(cur[i * 8 + 2], cur[i * 8 + 3]);
      pk.u[2] = pk2(cur[i * 8 + 4], cur[i * 8 + 5]);
      pk.u[3] = pk2(cur[i * 8 + 6], cur[i * 8 + 7]);
      *reinterpret_cast<s16x8*>(Bs + sst[i]) = pk.v;
    }
    // ---- issue P(it+2) into the just-freed buffer ----
    if (it + 2 < 4) {
#pragma unroll
      for (int i = 0; i < 2; ++i)
#pragma unroll
        for (int j = 0; j < 8; ++j) cur[i * 8 + j] = BLOAD(i, j, it + 2);
    }
    // ---- Bs visible to all waves (prefetches stay in flight) ----
    __builtin_amdgcn_sched_barrier(0);
    asm volatile("s_waitcnt lgkmcnt(0)" ::: "memory");
    __builtin_amdgcn_sched_barrier(0);
    __builtin_amdgcn_s_barrier();
    __builtin_amdgcn_sched_barrier(0);
    // ---- MFMA phase: 2 k-slices x 8 MFMA/wave ----
    __builtin_amdgcn_s_setprio(1);
#pragma unroll
    for (int ks = 0; ks < 2; ++ks) {
      s16x8 af[2], bf[4];
#pragma unroll
      for (int mf = 0; mf < 2; ++mf) {
        const int sc = (it * 8 + ks * 4 + lk) ^ (arow[mf] & 31);
        af[mf] = *reinterpret_cast<const s16x8*>(As + arow[mf] * 256 + 8 * sc);
      }
#pragma unroll
      for (int nf = 0; nf < 4; ++nf) {
        const int bc = (ks * 4 + lk) ^ (brow[nf] & 7);
        bf[nf] = *reinterpret_cast<const s16x8*>(Bs + brow[nf] * 64 + 8 * bc);
      }
#pragma unroll
      for (int mf = 0; mf < 2; ++mf)
#pragma unroll
        for (int nf = 0; nf < 4; ++nf)
          acc[mf][nf] = __builtin_amdgcn_mfma_f32_16x16x32_bf16(af[mf], bf[nf], acc[mf][nf], 0, 0, 0);
    }
    __builtin_amdgcn_s_setprio(0);
    // ---- protect Bs before next iter's overwrite ----
    __builtin_amdgcn_sched_barrier(0);
    __builtin_amdgcn_s_barrier();
    __builtin_amdgcn_sched_barrier(0);
  }
#undef BLOAD

  if (y == 0) {
    // q path: E = exp(q), [c][n] layout + row-sum partials
    ushort* C = Ecn + (size_t)b * 128 * NTOK + n0;
    float* sp = spart + (((size_t)b * 32 + ntile) * 2 + wc) * 128;
#pragma unroll
    for (int mf = 0; mf < 2; ++mf) {
#pragma unroll
      for (int r2_ = 0; r2_ < 4; ++r2_) {
        const int ch = wr * 32 + mf * 16 + lk * 4 + r2_;
        float s = 0.f;
#pragma unroll
        for (int nf = 0; nf < 4; ++nf) {
          const float e = __expf(acc[mf][nf][r2_]);
          s += e;
          C[(size_t)ch * NTOK + wc * 64 + nf * 16 + lm] = bf_rne(e);
        }
        s += __shfl_xor(s, 1, 64);
        s += __shfl_xor(s, 2, 64);
        s += __shfl_xor(s, 4, 64);
        s += __shfl_xor(s, 8, 64);
        if (lm == 0) sp[ch] = s;
      }
    }
  } else if (y == 1) {
    // k path: softmax over d (wave rows = one head, h = wr)
#pragma unroll
    for (int nf = 0; nf < 4; ++nf) {
      float m = -1e30f;
#pragma unroll
      for (int mf = 0; mf < 2; ++mf)
#pragma unroll
        for (int r2_ = 0; r2_ < 4; ++r2_)
          m = fmaxf(m, acc[mf][nf][r2_]);
      m = fmaxf(m, __shfl_xor(m, 16, 64));
      m = fmaxf(m, __shfl_xor(m, 32, 64));
      float s = 0.f;
#pragma unroll
      for (int mf = 0; mf < 2; ++mf)
#pragma unroll
        for (int r2_ = 0; r2_ < 4; ++r2_) {
          const float e = __expf(acc[mf][nf][r2_] - m);
          acc[mf][nf][r2_] = e;
          s += e;
        }
      s += __shfl_xor(s, 16, 64);
      s += __shfl_xor(s, 32, 64);
      const float inv = 1.0f / s;
#pragma unroll
      for (int mf = 0; mf < 2; ++mf)
#pragma unroll
        for (int r2_ = 0; r2_ < 4; ++r2_) acc[mf][nf][r2_] *= inv;
    }
    ushort* C = kb + (size_t)b * 128 * NTOK + n0;
#pragma unroll
    for (int mf = 0; mf < 2; ++mf) {
      const int row0 = wr * 32 + mf * 16 + lk * 4;
#pragma unroll
      for (int nf = 0; nf < 4; ++nf) {
        const int col = wc * 64 + nf * 16 + lm;
#pragma unroll
        for (int r2_ = 0; r2_ < 4; ++r2_)
          C[(size_t)(row0 + r2_) * NTOK + col] = bf_rne(acc[mf][nf][r2_]);
      }
    }
  } else {
    ushort* C = vb + (size_t)b * 128 * NTOK + n0;
#pragma unroll
    for (int mf = 0; mf < 2; ++mf) {
      const int row0 = wr * 32 + mf * 16 + lk * 4;
#pragma unroll
      for (int nf = 0; nf < 4; ++nf) {
        const int col = wc * 64 + nf * 16 + lm;
#pragma unroll
        for (int r2_ = 0; r2_ < 4; ++r2_)
          C[(size_t)(row0 + r2_) * NTOK + col] = bf_rne(acc[mf][nf][r2_]);
      }
    }
  }
}

// ---------------------------------------------------------------------------
// K2: context partials via bf16 MFMA. grid 256 = bh(128) x half(2);
// 4 waves x 512 tokens each -> 8 segments/bh (full CU coverage).
// ---------------------------------------------------------------------------
__global__ __launch_bounds__(256) void k_context_mfma(const ushort* __restrict__ kb,
                                                      const ushort* __restrict__ vb,
                                                      float* __restrict__ ctx_part) {
  const int bh = blockIdx.x >> 1;
  const int half = blockIdx.x & 1;
  const int w = threadIdx.x >> 6;
  const int seg = half * 4 + w;
  const int lane = threadIdx.x & 63;
  const int lm = lane & 15, lk = lane >> 4;
  const ushort* kp = kb + (size_t)bh * 32 * NTOK + (size_t)seg * 512;
  const ushort* vp = vb + (size_t)bh * 32 * NTOK + (size_t)seg * 512;
  f32x4 acc[2][2];
#pragma unroll
  for (int i = 0; i < 2; ++i)
#pragma unroll
    for (int j = 0; j < 2; ++j) acc[i][j] = (f32x4){0.f, 0.f, 0.f, 0.f};
#pragma unroll 4
  for (int ks = 0; ks < 16; ++ks) {
    const int coff = ks * 32 + lk * 8;
    const s16x8 a0 = *reinterpret_cast<const s16x8*>(kp + (size_t)lm * NTOK + coff);
    const s16x8 a1 = *reinterpret_cast<const s16x8*>(kp + (size_t)(16 + lm) * NTOK + coff);
    const s16x8 b0 = *reinterpret_cast<const s16x8*>(vp + (size_t)lm * NTOK + coff);
    const s16x8 b1 = *reinterpret_cast<const s16x8*>(vp + (size_t)(16 + lm) * NTOK + coff);
    acc[0][0] = __builtin_amdgcn_mfma_f32_16x16x32_bf16(a0, b0, acc[0][0], 0, 0, 0);
    acc[0][1] = __builtin_amdgcn_mfma_f32_16x16x32_bf16(a0, b1, acc[0][1], 0, 0, 0);
    acc[1][0] = __builtin_amdgcn_mfma_f32_16x16x32_bf16(a1, b0, acc[1][0], 0, 0, 0);
    acc[1][1] = __builtin_amdgcn_mfma_f32_16x16x32_bf16(a1, b1, acc[1][1], 0, 0, 0);
  }
  float* op = ctx_part + ((size_t)bh * 8 + seg) * 1024;
#pragma unroll
  for (int et = 0; et < 2; ++et)
#pragma unroll
    for (int dt = 0; dt < 2; ++dt)
#pragma unroll
      for (int r = 0; r < 4; ++r)
        op[(et * 16 + lk * 4 + r) * 32 + dt * 16 + lm] = acc[et][dt][r];
}

// ---------------------------------------------------------------------------
// K5: W2'[b][o][c'] = (sum_d w_out[o][h*32+d] * ctx[b][h][e][d]) * f[c'],
// f[c'] = SCALE / sum_n E[c'][n]. -> bf16. ctx sums 8 segment partials.
// ---------------------------------------------------------------------------
__global__ __launch_bounds__(256) void k_w2(const float* __restrict__ ctx_part,
                                            const float* __restrict__ spart,
                                            const float* __restrict__ w_out,
                                            ushort* __restrict__ W2b) {
  const int b = blockIdx.x;
  const int t = threadIdx.x;
  __shared__ float ctx[4096];
  __shared__ float fbuf[128];
#pragma unroll
  for (int i = 0; i < 16; ++i) {
    const int idx = t + 256 * i;
    const int h = idx >> 10, ed = idx & 1023;
    const float* cp = ctx_part + ((size_t)((b * 4 + h) * 8)) * 1024 + ed;
    float a = 0.f;
#pragma unroll
    for (int j = 0; j < 8; ++j) a += cp[j * 1024];
    ctx[idx] = a;
  }
  if (t < 128) {
    float s = 0.f;
    for (int p = 0; p < 64; ++p) s += spart[((size_t)b * 64 + p) * 128 + t];
    fbuf[t] = SCALE / s;
  }
  __syncthreads();
  const float* wrow = w_out + (size_t)t * 128;
  ushort* wout_row = W2b + ((size_t)b * 256 + t) * 128;
  float wv[32];
  for (int h = 0; h < 4; ++h) {
#pragma unroll
    for (int d = 0; d < 32; ++d) wv[d] = wrow[h * 32 + d];
#pragma unroll 4
    for (int e = 0; e < 32; ++e) {
      float a = 0.f;
#pragma unroll
      for (int d = 0; d < 32; ++d) a += wv[d] * ctx[h * 1024 + e * 32 + d];
      wout_row[h * 32 + e] = bf_rne(a * fbuf[h * 32 + e]);
    }
  }
}

// ---------------------------------------------------------------------------
// K6: out[b][o][n] = sum_c W2'[b][o][c] * E[b][c][n] + b_out[o], bf16 MFMA.
// BK=64, 2 iters. A via gl_lds (swizzled source), B gather staged.
// grid (32, 2, 32).  (at memory roofline: 134 MB fp32 output write)
// ---------------------------------------------------------------------------
__global__ __launch_bounds__(256) void k_out_mfma(const ushort* __restrict__ Ecn,
                                                  const ushort* __restrict__ W2b,
                                                  const float* __restrict__ b_out,
                                                  float* __restrict__ out) {
  const int n0 = blockIdx.x * 128;
  const int o0 = blockIdx.y * 128;
  const int b  = blockIdx.z;
  const ushort* A  = W2b + (size_t)b * 256 * 128;
  const ushort* Bq = Ecn + (size_t)b * 128 * NTOK;

  __shared__ ushort As[8192];
  __shared__ ushort Bt[8192];

  const int t = threadIdx.x;
  const int lane = t & 63;
  const int wv = t >> 6;
  const int wr = wv >> 1, wc = wv & 1;
  const int lm = lane & 15;
  const int lk = lane >> 4;

  int aoff[4][2], boff[4][2];
#pragma unroll
  for (int mf = 0; mf < 4; ++mf) {
    const int ar = wr * 64 + mf * 16 + lm;
#pragma unroll
    for (int ks = 0; ks < 2; ++ks)
      aoff[mf][ks] = ar * 64 + 8 * ((ks * 4 + lk) ^ (ar & 7));
  }
#pragma unroll
  for (int nf = 0; nf < 4; ++nf) {
    const int br = wc * 64 + nf * 16 + lm;
#pragma unroll
    for (int ks = 0; ks < 2; ++ks)
      boff[nf][ks] = br * 64 + 8 * ((ks * 4 + lk) ^ (br & 7));
  }
  size_t gaA[4];
  int lb[4];
#pragma unroll
  for (int i = 0; i < 4; ++i) {
    const int s_total = t + 256 * i;
    const int r = s_total >> 3;
    const int q = (s_total & 7) ^ (r & 7);
    gaA[i] = (size_t)(o0 + r) * 128 + q * 8;
    lb[i] = wv * 512 + i * 2048;
  }
  int bst[8], bn[8], bcg[8];
#pragma unroll
  for (int i = 0; i < 8; ++i) {
    const int u = t + 256 * i;
    bn[i] = u & 127;
    bcg[i] = u >> 7;
    bst[i] = bn[i] * 64 + 8 * ((bcg[i] >> 1) ^ (bn[i] & 7)) + (bcg[i] & 1) * 4;
  }

  f32x4 acc[4][4];
#pragma unroll
  for (int i = 0; i < 4; ++i)
#pragma unroll
    for (int j = 0; j < 4; ++j) acc[i][j] = (f32x4){0.f, 0.f, 0.f, 0.f};

  for (int it = 0; it < 2; ++it) {
    const size_t c0 = (size_t)it * 64;
    __syncthreads();
#pragma unroll
    for (int i = 0; i < 4; ++i)
      gl_lds16(A + gaA[i] + c0, As + lb[i]);
#pragma unroll
    for (int i = 0; i < 8; ++i) {
      const ushort* gp = Bq + (c0 + bcg[i] * 4) * NTOK + n0 + bn[i];
      ushort4 hvec;
      hvec.x = gp[0];
      hvec.y = gp[NTOK];
      hvec.z = gp[2 * NTOK];
      hvec.w = gp[3 * NTOK];
      *reinterpret_cast<ushort4*>(Bt + bst[i]) = hvec;
    }
    __syncthreads();
#pragma unroll
    for (int ks = 0; ks < 2; ++ks) {
      s16x8 af[4], bf[4];
#pragma unroll
      for (int mf = 0; mf < 4; ++mf)
        af[mf] = *reinterpret_cast<const s16x8*>(As + aoff[mf][ks]);
#pragma unroll
      for (int nf = 0; nf < 4; ++nf)
        bf[nf] = *reinterpret_cast<const s16x8*>(Bt + boff[nf][ks]);
#pragma unroll
      for (int mf = 0; mf < 4; ++mf)
#pragma unroll
        for (int nf = 0; nf < 4; ++nf)
          acc[mf][nf] = __builtin_amdgcn_mfma_f32_16x16x32_bf16(af[mf], bf[nf], acc[mf][nf], 0, 0, 0);
    }
  }

  float* C = out + ((size_t)b * 256 + o0) * NTOK + n0;
#pragma unroll
  for (int mf = 0; mf < 4; ++mf) {
    const int row0 = wr * 64 + mf * 16 + lk * 4;
#pragma unroll
    for (int nf = 0; nf < 4; ++nf) {
      const int col = wc * 64 + nf * 16 + lm;
#pragma unroll
      for (int r = 0; r < 4; ++r) {
        const float bias = b_out[o0 + row0 + r];
        C[(size_t)(row0 + r) * NTOK + col] = acc[mf][nf][r] + bias;
      }
    }
  }
}

extern "C" void kernel_launch(void* const* d_in, const int* in_sizes, int n_in,
                              void* d_out, int out_size, void* d_ws, size_t ws_size,
                              hipStream_t stream) {
  const float* x     = (const float*)d_in[0];
  const float* w_qkv = (const float*)d_in[1];
  const float* w_out = (const float*)d_in[2];
  const float* b_out = (const float*)d_in[3];
  float* out = (float*)d_out;

  ushort* kb  = (ushort*)d_ws;                          // 16777216 us (33.5MB)
  ushort* vb  = kb + (size_t)16777216;                  // 33.5MB
  ushort* Ecn = vb + (size_t)16777216;                  // 33.5MB
  float*  ctx_part = (float*)(Ecn + (size_t)16777216);  // 1048576 f32 (4MB)
  float*  spart    = ctx_part + 1048576;                // 262144 f32 (1MB)
  ushort* wb  = (ushort*)(spart + 262144);              // 98304 us
  ushort* W2b = wb + 98304;                             // 1048576 us (2MB)

  k_cvt_w<<<96, 256, 0, stream>>>(w_qkv, wb);
  k_qkv_mfma<<<dim3(96, 32), 512, 0, stream>>>(x, wb, Ecn, kb, vb, spart);
  k_context_mfma<<<256, 256, 0, stream>>>(kb, vb, ctx_part);
  k_w2<<<32, 256, 0, stream>>>(ctx_part, spart, w_out, W2b);
  k_out_mfma<<<dim3(32, 2, 32), 256, 0, stream>>>(Ecn, W2b, b_out, out);
}